// Round 1
// baseline (531.462 us; speedup 1.0000x reference)
//
#include <hip/hip_runtime.h>
#include <hip/hip_bf16.h>
#include <math.h>

typedef __bf16 bf16_t;
typedef __bf16 bf16x8 __attribute__((ext_vector_type(8)));
typedef __bf16 bf16x4 __attribute__((ext_vector_type(4)));
typedef float  f32x4  __attribute__((ext_vector_type(4)));
typedef unsigned int u32;

static constexpr int C_    = 1024;
static constexpr int NH    = 16;
static constexpr int DH    = 64;
static constexpr int BB    = 2;
static constexpr int TT    = 2048;
static constexpr int MROWS = BB * TT;   // 4096

// ---------------- async global->LDS, 16B per lane, wave-uniform LDS base ----
__device__ __forceinline__ void gload_lds16(const bf16_t* src, bf16_t* dst) {
  __builtin_amdgcn_global_load_lds(
      (const __attribute__((address_space(1))) u32*)(src),
      (__attribute__((address_space(3))) u32*)(dst),
      16, 0, 0);
}

// ---------------- LayerNorm (fp32 in) -> bf16 out ---------------------------
__global__ __launch_bounds__(256) void ln_bf16(
    const float* __restrict__ x, const float* __restrict__ w,
    const float* __restrict__ b, bf16_t* __restrict__ out)
{
  const int row = blockIdx.x;
  const int tid = threadIdx.x;
  const float4 v = reinterpret_cast<const float4*>(x + (size_t)row * C_)[tid];
  float s  = v.x + v.y + v.z + v.w;
  float s2 = v.x*v.x + v.y*v.y + v.z*v.z + v.w*v.w;
#pragma unroll
  for (int m = 1; m < 64; m <<= 1) { s += __shfl_xor(s, m); s2 += __shfl_xor(s2, m); }
  __shared__ float red[8];
  const int wv = tid >> 6;
  if ((tid & 63) == 0) { red[wv] = s; red[4 + wv] = s2; }
  __syncthreads();
  s  = red[0] + red[1] + red[2] + red[3];
  s2 = red[4] + red[5] + red[6] + red[7];
  const float mu   = s * (1.0f / C_);
  const float rstd = rsqrtf(s2 * (1.0f / C_) - mu * mu + 1e-5f);
  const float4 wv4 = reinterpret_cast<const float4*>(w)[tid];
  const float4 bv4 = reinterpret_cast<const float4*>(b)[tid];
  bf16x4 o;
  o[0] = (bf16_t)((v.x - mu) * rstd * wv4.x + bv4.x);
  o[1] = (bf16_t)((v.y - mu) * rstd * wv4.y + bv4.y);
  o[2] = (bf16_t)((v.z - mu) * rstd * wv4.z + bv4.z);
  o[3] = (bf16_t)((v.w - mu) * rstd * wv4.w + bv4.w);
  *reinterpret_cast<bf16x4*>(out + (size_t)row * C_ + tid * 4) = o;
}

// ---------------- weight transpose+convert: fp32 [K][N] -> bf16 [N][K] ------
__global__ __launch_bounds__(256) void transpose_w(
    const float* __restrict__ in, bf16_t* __restrict__ out, int K, int N)
{
  __shared__ float tile[32][33];
  const int tx = threadIdx.x & 31, ty = threadIdx.x >> 5;
  const int n0 = blockIdx.x * 32, k0 = blockIdx.y * 32;
#pragma unroll
  for (int i = 0; i < 4; ++i)
    tile[ty + i * 8][tx] = in[(size_t)(k0 + ty + i * 8) * N + n0 + tx];
  __syncthreads();
#pragma unroll
  for (int i = 0; i < 4; ++i)
    out[(size_t)(n0 + ty + i * 8) * K + k0 + tx] = (bf16_t)tile[tx][ty + i * 8];
}

// ---------------- V transpose: bf16 [BH][T][D] -> [BH][D][T] -----------------
__global__ __launch_bounds__(256) void transpose_v(
    const bf16_t* __restrict__ in, bf16_t* __restrict__ out)
{
  __shared__ bf16_t tile[32][33];
  const int bh = blockIdx.z;
  const bf16_t* src = in  + (size_t)bh * TT * DH;
  bf16_t*       dst = out + (size_t)bh * TT * DH;
  const int tx = threadIdx.x & 31, ty = threadIdx.x >> 5;
  const int t0 = blockIdx.x * 32, d0 = blockIdx.y * 32;
#pragma unroll
  for (int i = 0; i < 4; ++i)
    tile[ty + i * 8][tx] = src[(size_t)(t0 + ty + i * 8) * DH + d0 + tx];
  __syncthreads();
#pragma unroll
  for (int i = 0; i < 4; ++i)
    dst[(size_t)(d0 + ty + i * 8) * TT + t0 + tx] = tile[tx][ty + i * 8];
}

// ---------------- GEMM: C = A[M][K] * Bt[N][K]^T + bias, epilogues ----------
// EPI 0: qkv scatter -> q/k/v [B,H,T,D] bf16
// EPI 1: + resid -> fp32 out
// EPI 2: gelu -> bf16 out
template<int EPI>
__global__ __launch_bounds__(256) void gemm_bf16(
    const bf16_t* __restrict__ A, const bf16_t* __restrict__ Bt,
    const float* __restrict__ bias, const float* __restrict__ resid,
    float* __restrict__ fout, bf16_t* __restrict__ bout0,
    bf16_t* __restrict__ bout1, bf16_t* __restrict__ bout2,
    int M, int N, int K)
{
  constexpr int BM = 128, BN = 128, BK = 64;
  __shared__ bf16_t As[BM * BK];
  __shared__ bf16_t Bs[BN * BK];
  const int tid  = threadIdx.x;
  const int wave = tid >> 6, lane = tid & 63;
  const int r = lane & 15, g = lane >> 4;
  const int wm = wave >> 1, wn = wave & 1;
  const int bm = blockIdx.x, bn = blockIdx.y;

  const bf16_t* Abase = A  + (size_t)bm * BM * K;
  const bf16_t* Bbase = Bt + (size_t)bn * BN * K;

  f32x4 acc[4][4] = {};

  for (int kt = 0; kt < K; kt += BK) {
    // stage A tile (128x64 bf16, 1024 16B chunks), inverse-swizzled source
#pragma unroll
    for (int it = 0; it < 4; ++it) {
      const int c0 = it * 256 + wave * 64;
      const int idx = c0 + lane;
      const int rr = idx >> 3, cc = idx & 7;
      const int gs = cc ^ (rr & 7);
      gload_lds16(Abase + (size_t)rr * K + kt + gs * 8, As + c0 * 8);
    }
#pragma unroll
    for (int it = 0; it < 4; ++it) {
      const int c0 = it * 256 + wave * 64;
      const int idx = c0 + lane;
      const int rr = idx >> 3, cc = idx & 7;
      const int gs = cc ^ (rr & 7);
      gload_lds16(Bbase + (size_t)rr * K + kt + gs * 8, Bs + c0 * 8);
    }
    asm volatile("s_waitcnt vmcnt(0)" ::: "memory");
    __syncthreads();
#pragma unroll
    for (int s = 0; s < 2; ++s) {
      bf16x8 af[4], bfr[4];
#pragma unroll
      for (int mi = 0; mi < 4; ++mi) {
        const int rr = wm * 64 + mi * 16 + r;
        const int ch = (s * 4 + g) ^ (rr & 7);
        af[mi] = *reinterpret_cast<const bf16x8*>(&As[rr * BK + ch * 8]);
      }
#pragma unroll
      for (int ni = 0; ni < 4; ++ni) {
        const int rr = wn * 64 + ni * 16 + r;
        const int ch = (s * 4 + g) ^ (rr & 7);
        bfr[ni] = *reinterpret_cast<const bf16x8*>(&Bs[rr * BK + ch * 8]);
      }
#pragma unroll
      for (int mi = 0; mi < 4; ++mi)
#pragma unroll
        for (int ni = 0; ni < 4; ++ni)
          acc[mi][ni] = __builtin_amdgcn_mfma_f32_16x16x32_bf16(
              af[mi], bfr[ni], acc[mi][ni], 0, 0, 0);
    }
    __syncthreads();
  }

  // epilogue: lane holds D[row=(g*4+i)+16*mi (+64*wm)][col=r+16*ni (+64*wn)]
#pragma unroll
  for (int mi = 0; mi < 4; ++mi) {
#pragma unroll
    for (int ni = 0; ni < 4; ++ni) {
      const int grow0 = bm * BM + wm * 64 + mi * 16 + g * 4;
      const int gcol  = bn * BN + wn * 64 + ni * 16 + r;
      const float bv = bias[gcol];
#pragma unroll
      for (int i = 0; i < 4; ++i) {
        const int grow = grow0 + i;
        float v = acc[mi][ni][i] + bv;
        if constexpr (EPI == 0) {
          const int which = gcol >> 10;
          const int c0 = gcol & 1023;
          const int hh = c0 >> 6, dd = c0 & 63;
          const int bb = grow >> 11, t = grow & 2047;
          bf16_t* dst = (which == 0) ? bout0 : (which == 1) ? bout1 : bout2;
          dst[((size_t)(bb * NH + hh) * TT + t) * DH + dd] = (bf16_t)v;
        } else if constexpr (EPI == 1) {
          const size_t o = (size_t)grow * N + gcol;
          fout[o] = v + resid[o];
        } else {
          const float gl = 0.5f * v * (1.0f + erff(v * 0.70710678118654752f));
          bout0[(size_t)grow * N + gcol] = (bf16_t)gl;
        }
      }
    }
  }
}

// ---------------- two-pass causal attention with per-head LIF gating --------
__global__ __launch_bounds__(256) void attn_lif(
    const bf16_t* __restrict__ Q, const bf16_t* __restrict__ Km,
    const bf16_t* __restrict__ Vt, bf16_t* __restrict__ Y,
    const float* __restrict__ thrp, const float* __restrict__ leakp,
    const float* __restrict__ steepp)
{
  constexpr int QT = 128, KT = 64;
  __shared__ bf16_t Ks[KT * DH];      // keys x d, swizzled
  __shared__ bf16_t Vs[DH * KT];      // d x keys, swizzled
  __shared__ bf16_t Ms[4][32 * KT];   // per-wave gated-m tile, swizzled
  const int tid = threadIdx.x;
  const int wave = tid >> 6, lane = tid & 63;
  const int r = lane & 15, g = lane >> 4;
  const int qt = blockIdx.x, bh = blockIdx.y;
  const int hh = bh & (NH - 1);
  const int bb = bh >> 4;

  const bf16_t* Qh  = Q  + (size_t)bh * TT * DH;
  const bf16_t* Kh  = Km + (size_t)bh * TT * DH;
  const bf16_t* Vth = Vt + (size_t)bh * TT * DH;  // [DH][TT]

  const float th = fabsf(thrp[hh]) * 0.1f;
  const float lk = 1.0f / (1.0f + expf(-leakp[hh]));
  const float st = log1pf(expf(steepp[hh]));

  // Q fragments held in registers for the whole kernel
  bf16x8 qf[2][2];
#pragma unroll
  for (int mi = 0; mi < 2; ++mi)
#pragma unroll
    for (int s = 0; s < 2; ++s) {
      const int qrow = qt * QT + wave * 32 + mi * 16 + r;
      qf[mi][s] = *reinterpret_cast<const bf16x8*>(Qh + (size_t)qrow * DH + s * 32 + g * 8);
    }

  const int qmaxWave = qt * QT + wave * 32 + 31;
  const int nkt = 2 * qt + 2;

  float runM[2][4], runZ[2][4];
#pragma unroll
  for (int mi = 0; mi < 2; ++mi)
#pragma unroll
    for (int i = 0; i < 4; ++i) { runM[mi][i] = -1e30f; runZ[mi][i] = 0.f; }

  // ---- pass 1: row max and Z
  for (int kt = 0; kt < nkt; ++kt) {
#pragma unroll
    for (int it = 0; it < 2; ++it) {
      const int c0 = it * 256 + wave * 64;
      const int idx = c0 + lane;
      const int rr = idx >> 3, cc = idx & 7;
      const int gs = cc ^ (rr & 7);
      gload_lds16(Kh + (size_t)(kt * KT + rr) * DH + gs * 8, Ks + c0 * 8);
    }
    asm volatile("s_waitcnt vmcnt(0)" ::: "memory");
    __syncthreads();
    if (kt * KT <= qmaxWave) {
      f32x4 sf[2][4] = {};
#pragma unroll
      for (int s = 0; s < 2; ++s) {
        bf16x8 kf[4];
#pragma unroll
        for (int ni = 0; ni < 4; ++ni) {
          const int rr = ni * 16 + r;
          const int ch = (s * 4 + g) ^ (rr & 7);
          kf[ni] = *reinterpret_cast<const bf16x8*>(&Ks[rr * DH + ch * 8]);
        }
#pragma unroll
        for (int mi = 0; mi < 2; ++mi)
#pragma unroll
          for (int ni = 0; ni < 4; ++ni)
            sf[mi][ni] = __builtin_amdgcn_mfma_f32_16x16x32_bf16(
                qf[mi][s], kf[ni], sf[mi][ni], 0, 0, 0);
      }
#pragma unroll
      for (int mi = 0; mi < 2; ++mi) {
#pragma unroll
        for (int i = 0; i < 4; ++i) {
          const int qrow = qt * QT + wave * 32 + mi * 16 + g * 4 + i;
          float sv[4];
          float mx = -1e30f;
#pragma unroll
          for (int ni = 0; ni < 4; ++ni) {
            const int kcol = kt * KT + ni * 16 + r;
            float xv = sf[mi][ni][i] * 0.125f;
            if (kcol > qrow) xv = -1e30f;
            sv[ni] = xv;
            mx = fmaxf(mx, xv);
          }
#pragma unroll
          for (int m2 = 1; m2 < 16; m2 <<= 1) mx = fmaxf(mx, __shfl_xor(mx, m2));
          const float nm = fmaxf(runM[mi][i], mx);
          float se = 0.f;
#pragma unroll
          for (int ni = 0; ni < 4; ++ni) se += __expf(sv[ni] - nm);
#pragma unroll
          for (int m2 = 1; m2 < 16; m2 <<= 1) se += __shfl_xor(se, m2);
          runZ[mi][i] = runZ[mi][i] * __expf(runM[mi][i] - nm) + se;
          runM[mi][i] = nm;
        }
      }
    }
    __syncthreads();
  }

  float rcpZ[2][4];
#pragma unroll
  for (int mi = 0; mi < 2; ++mi)
#pragma unroll
    for (int i = 0; i < 4; ++i) rcpZ[mi][i] = 1.0f / runZ[mi][i];

  // ---- pass 2: p, LIF gate, m@V, sum(m)
  f32x4 yacc[2][4] = {};
  float den[2][4] = {};
  for (int kt = 0; kt < nkt; ++kt) {
#pragma unroll
    for (int it = 0; it < 2; ++it) {
      const int c0 = it * 256 + wave * 64;
      const int idx = c0 + lane;
      const int rr = idx >> 3, cc = idx & 7;
      const int gs = cc ^ (rr & 7);
      gload_lds16(Kh + (size_t)(kt * KT + rr) * DH + gs * 8, Ks + c0 * 8);
    }
#pragma unroll
    for (int it = 0; it < 2; ++it) {
      const int c0 = it * 256 + wave * 64;
      const int idx = c0 + lane;
      const int rr = idx >> 3, cc = idx & 7;
      const int gs = cc ^ (rr & 7);
      gload_lds16(Vth + (size_t)rr * TT + kt * KT + gs * 8, Vs + c0 * 8);
    }
    asm volatile("s_waitcnt vmcnt(0)" ::: "memory");
    __syncthreads();
    const bool act = (kt * KT <= qmaxWave);
    if (act) {
      f32x4 sf[2][4] = {};
#pragma unroll
      for (int s = 0; s < 2; ++s) {
        bf16x8 kf[4];
#pragma unroll
        for (int ni = 0; ni < 4; ++ni) {
          const int rr = ni * 16 + r;
          const int ch = (s * 4 + g) ^ (rr & 7);
          kf[ni] = *reinterpret_cast<const bf16x8*>(&Ks[rr * DH + ch * 8]);
        }
#pragma unroll
        for (int mi = 0; mi < 2; ++mi)
#pragma unroll
          for (int ni = 0; ni < 4; ++ni)
            sf[mi][ni] = __builtin_amdgcn_mfma_f32_16x16x32_bf16(
                qf[mi][s], kf[ni], sf[mi][ni], 0, 0, 0);
      }
      bf16_t* mw = &Ms[wave][0];
#pragma unroll
      for (int mi = 0; mi < 2; ++mi)
#pragma unroll
        for (int i = 0; i < 4; ++i) {
          const int qrow = qt * QT + wave * 32 + mi * 16 + g * 4 + i;
          const int rr = mi * 16 + g * 4 + i;
#pragma unroll
          for (int ni = 0; ni < 4; ++ni) {
            const int kcol = kt * KT + ni * 16 + r;
            const float xv = sf[mi][ni][i] * 0.125f;
            const float p = (kcol > qrow) ? 0.f
                          : __expf(xv - runM[mi][i]) * rcpZ[mi][i];
            const float fire = 1.0f / (1.0f + __expf(-st * (p - th)));
            const float mv = p * (lk + (1.0f - lk) * fire);
            den[mi][i] += mv;
            const int cc2 = ni * 16 + r;
            const int ch = (cc2 >> 3) ^ (rr & 7);
            mw[rr * KT + ch * 8 + (cc2 & 7)] = (bf16_t)mv;
          }
        }
    }
    __syncthreads();  // m visible (and wave-aligned) before PV reads
    if (act) {
      const bf16_t* mrd = &Ms[wave][0];
#pragma unroll
      for (int s = 0; s < 2; ++s) {
        bf16x8 mf[2], vf[4];
#pragma unroll
        for (int mi = 0; mi < 2; ++mi) {
          const int rr = mi * 16 + r;
          const int ch = (s * 4 + g) ^ (rr & 7);
          mf[mi] = *reinterpret_cast<const bf16x8*>(&mrd[rr * KT + ch * 8]);
        }
#pragma unroll
        for (int ni = 0; ni < 4; ++ni) {
          const int rr = ni * 16 + r;
          const int ch = (s * 4 + g) ^ (rr & 7);
          vf[ni] = *reinterpret_cast<const bf16x8*>(&Vs[rr * KT + ch * 8]);
        }
#pragma unroll
        for (int mi = 0; mi < 2; ++mi)
#pragma unroll
          for (int ni = 0; ni < 4; ++ni)
            yacc[mi][ni] = __builtin_amdgcn_mfma_f32_16x16x32_bf16(
                mf[mi], vf[ni], yacc[mi][ni], 0, 0, 0);
      }
    }
    __syncthreads();
  }

  // renormalize and write Y as [B][T][H*D]
#pragma unroll
  for (int mi = 0; mi < 2; ++mi)
#pragma unroll
    for (int i = 0; i < 4; ++i) {
      float d = den[mi][i];
#pragma unroll
      for (int m2 = 1; m2 < 16; m2 <<= 1) d += __shfl_xor(d, m2);
      den[mi][i] = 1.0f / (d + 1e-8f);
    }
#pragma unroll
  for (int mi = 0; mi < 2; ++mi)
#pragma unroll
    for (int ni = 0; ni < 4; ++ni)
#pragma unroll
      for (int i = 0; i < 4; ++i) {
        const int t  = qt * QT + wave * 32 + mi * 16 + g * 4 + i;
        const int dd = ni * 16 + r;
        const float yv = yacc[mi][ni][i] * den[mi][i];
        Y[((size_t)(bb * TT + t)) * C_ + hh * DH + dd] = (bf16_t)yv;
      }
}

// ---------------------------------------------------------------------------
extern "C" void kernel_launch(void* const* d_in, const int* in_sizes, int n_in,
                              void* d_out, int out_size, void* d_ws, size_t ws_size,
                              hipStream_t stream)
{
  const float* x      = (const float*)d_in[0];
  const float* ln1_w  = (const float*)d_in[1];
  const float* ln1_b  = (const float*)d_in[2];
  const float* w_attn = (const float*)d_in[3];
  const float* b_attn = (const float*)d_in[4];
  const float* w_proj = (const float*)d_in[5];
  const float* b_proj = (const float*)d_in[6];
  const float* thr    = (const float*)d_in[7];
  const float* leak   = (const float*)d_in[8];
  const float* steep  = (const float*)d_in[9];
  const float* ln2_w  = (const float*)d_in[10];
  const float* ln2_b  = (const float*)d_in[11];
  const float* w_fc   = (const float*)d_in[12];
  const float* b_fc   = (const float*)d_in[13];
  const float* w_mlp  = (const float*)d_in[14];
  const float* b_mlp  = (const float*)d_in[15];

  char* ws = (char*)d_ws;
  bf16_t* q    = (bf16_t*)(ws + 0);          //  8 MB
  bf16_t* k    = (bf16_t*)(ws + 8388608);    //  8 MB
  bf16_t* v    = (bf16_t*)(ws + 16777216);   //  8 MB
  bf16_t* vT   = (bf16_t*)(ws + 25165824);   //  8 MB
  bf16_t* gbuf = (bf16_t*)(ws + 0);          // 32 MB, aliases q/k/v/vT (dead)
  bf16_t* hbuf = (bf16_t*)(ws + 33554432);   //  8 MB, h -> y -> h2
  float*  x2   = (float*) (ws + 41943040);   // 16 MB
  bf16_t* wT_attn = (bf16_t*)(ws + 58720256); // 6 MB
  bf16_t* wT_proj = (bf16_t*)(ws + 65011712); // 2 MB
  bf16_t* wT_fc   = (bf16_t*)(ws + 67108864); // 8 MB
  bf16_t* wT_mlp  = (bf16_t*)(ws + 75497472); // 8 MB -> 80 MB total

  float* out = (float*)d_out;

  // LN1 and weight preparation
  ln_bf16<<<dim3(MROWS), dim3(256), 0, stream>>>(x, ln1_w, ln1_b, hbuf);
  transpose_w<<<dim3(96, 32),  dim3(256), 0, stream>>>(w_attn, wT_attn, 1024, 3072);
  transpose_w<<<dim3(32, 32),  dim3(256), 0, stream>>>(w_proj, wT_proj, 1024, 1024);
  transpose_w<<<dim3(128, 32), dim3(256), 0, stream>>>(w_fc,   wT_fc,   1024, 4096);
  transpose_w<<<dim3(32, 128), dim3(256), 0, stream>>>(w_mlp,  wT_mlp,  4096, 1024);

  // QKV
  gemm_bf16<0><<<dim3(32, 24), dim3(256), 0, stream>>>(
      hbuf, wT_attn, b_attn, nullptr, nullptr, q, k, v, MROWS, 3072, 1024);
  transpose_v<<<dim3(64, 2, 32), dim3(256), 0, stream>>>(v, vT);

  // attention (+LIF gate + renorm), y -> hbuf
  attn_lif<<<dim3(16, 32), dim3(256), 0, stream>>>(q, k, vT, hbuf, thr, leak, steep);

  // attn projection + residual -> x2 (fp32)
  gemm_bf16<1><<<dim3(32, 8), dim3(256), 0, stream>>>(
      hbuf, wT_proj, b_proj, x, x2, nullptr, nullptr, nullptr, MROWS, 1024, 1024);

  // LN2 -> hbuf
  ln_bf16<<<dim3(MROWS), dim3(256), 0, stream>>>(x2, ln2_w, ln2_b, hbuf);

  // MLP fc + exact GELU -> gbuf
  gemm_bf16<2><<<dim3(32, 32), dim3(256), 0, stream>>>(
      hbuf, wT_fc, b_fc, nullptr, nullptr, gbuf, nullptr, nullptr, MROWS, 4096, 1024);

  // MLP proj + residual -> out (fp32)
  gemm_bf16<1><<<dim3(32, 8), dim3(256), 0, stream>>>(
      gbuf, wT_mlp, b_mlp, x2, out, nullptr, nullptr, nullptr, MROWS, 1024, 4096);
}

// Round 2
// 430.943 us; speedup vs baseline: 1.2333x; 1.2333x over previous
//
#include <hip/hip_runtime.h>
#include <hip/hip_bf16.h>
#include <math.h>

typedef __bf16 bf16_t;
typedef __bf16 bf16x8 __attribute__((ext_vector_type(8)));
typedef __bf16 bf16x4 __attribute__((ext_vector_type(4)));
typedef float  f32x4  __attribute__((ext_vector_type(4)));
typedef unsigned int u32;

static constexpr int C_    = 1024;
static constexpr int NH    = 16;
static constexpr int DH    = 64;
static constexpr int BB    = 2;
static constexpr int TT    = 2048;
static constexpr int MROWS = BB * TT;   // 4096

// ---------------- async global->LDS, 16B per lane, wave-uniform LDS base ----
__device__ __forceinline__ void gload_lds16(const bf16_t* src, bf16_t* dst) {
  __builtin_amdgcn_global_load_lds(
      (const __attribute__((address_space(1))) u32*)(src),
      (__attribute__((address_space(3))) u32*)(dst),
      16, 0, 0);
}

// ---------------- LayerNorm (fp32 in) -> bf16 out ---------------------------
__global__ __launch_bounds__(256) void ln_bf16(
    const float* __restrict__ x, const float* __restrict__ w,
    const float* __restrict__ b, bf16_t* __restrict__ out)
{
  const int row = blockIdx.x;
  const int tid = threadIdx.x;
  const float4 v = reinterpret_cast<const float4*>(x + (size_t)row * C_)[tid];
  float s  = v.x + v.y + v.z + v.w;
  float s2 = v.x*v.x + v.y*v.y + v.z*v.z + v.w*v.w;
#pragma unroll
  for (int m = 1; m < 64; m <<= 1) { s += __shfl_xor(s, m); s2 += __shfl_xor(s2, m); }
  __shared__ float red[8];
  const int wv = tid >> 6;
  if ((tid & 63) == 0) { red[wv] = s; red[4 + wv] = s2; }
  __syncthreads();
  s  = red[0] + red[1] + red[2] + red[3];
  s2 = red[4] + red[5] + red[6] + red[7];
  const float mu   = s * (1.0f / C_);
  const float rstd = rsqrtf(s2 * (1.0f / C_) - mu * mu + 1e-5f);
  const float4 wv4 = reinterpret_cast<const float4*>(w)[tid];
  const float4 bv4 = reinterpret_cast<const float4*>(b)[tid];
  bf16x4 o;
  o[0] = (bf16_t)((v.x - mu) * rstd * wv4.x + bv4.x);
  o[1] = (bf16_t)((v.y - mu) * rstd * wv4.y + bv4.y);
  o[2] = (bf16_t)((v.z - mu) * rstd * wv4.z + bv4.z);
  o[3] = (bf16_t)((v.w - mu) * rstd * wv4.w + bv4.w);
  *reinterpret_cast<bf16x4*>(out + (size_t)row * C_ + tid * 4) = o;
}

// ---------------- weight transpose+convert: fp32 [K][N] -> bf16 [N][K] ------
__global__ __launch_bounds__(256) void transpose_w(
    const float* __restrict__ in, bf16_t* __restrict__ out, int K, int N)
{
  __shared__ float tile[32][33];
  const int tx = threadIdx.x & 31, ty = threadIdx.x >> 5;
  const int n0 = blockIdx.x * 32, k0 = blockIdx.y * 32;
#pragma unroll
  for (int i = 0; i < 4; ++i)
    tile[ty + i * 8][tx] = in[(size_t)(k0 + ty + i * 8) * N + n0 + tx];
  __syncthreads();
#pragma unroll
  for (int i = 0; i < 4; ++i)
    out[(size_t)(n0 + ty + i * 8) * K + k0 + tx] = (bf16_t)tile[tx][ty + i * 8];
}

// ---------------- V transpose: bf16 [BH][T][D] -> [BH][D][T] -----------------
__global__ __launch_bounds__(256) void transpose_v(
    const bf16_t* __restrict__ in, bf16_t* __restrict__ out)
{
  __shared__ bf16_t tile[32][33];
  const int bh = blockIdx.z;
  const bf16_t* src = in  + (size_t)bh * TT * DH;
  bf16_t*       dst = out + (size_t)bh * TT * DH;
  const int tx = threadIdx.x & 31, ty = threadIdx.x >> 5;
  const int t0 = blockIdx.x * 32, d0 = blockIdx.y * 32;
#pragma unroll
  for (int i = 0; i < 4; ++i)
    tile[ty + i * 8][tx] = src[(size_t)(t0 + ty + i * 8) * DH + d0 + tx];
  __syncthreads();
#pragma unroll
  for (int i = 0; i < 4; ++i)
    dst[(size_t)(d0 + ty + i * 8) * TT + t0 + tx] = tile[tx][ty + i * 8];
}

// ---------------- GEMM: C = A[M][K] * Bt[N][K]^T + bias, epilogues ----------
template<int EPI>
__global__ __launch_bounds__(256) void gemm_bf16(
    const bf16_t* __restrict__ A, const bf16_t* __restrict__ Bt,
    const float* __restrict__ bias, const float* __restrict__ resid,
    float* __restrict__ fout, bf16_t* __restrict__ bout0,
    bf16_t* __restrict__ bout1, bf16_t* __restrict__ bout2,
    int M, int N, int K)
{
  constexpr int BM = 128, BN = 128, BK = 64;
  __shared__ bf16_t As[BM * BK];
  __shared__ bf16_t Bs[BN * BK];
  const int tid  = threadIdx.x;
  const int wave = tid >> 6, lane = tid & 63;
  const int r = lane & 15, g = lane >> 4;
  const int wm = wave >> 1, wn = wave & 1;
  const int bm = blockIdx.x, bn = blockIdx.y;

  const bf16_t* Abase = A  + (size_t)bm * BM * K;
  const bf16_t* Bbase = Bt + (size_t)bn * BN * K;

  f32x4 acc[4][4] = {};

  for (int kt = 0; kt < K; kt += BK) {
#pragma unroll
    for (int it = 0; it < 4; ++it) {
      const int c0 = it * 256 + wave * 64;
      const int idx = c0 + lane;
      const int rr = idx >> 3, cc = idx & 7;
      const int gs = cc ^ (rr & 7);
      gload_lds16(Abase + (size_t)rr * K + kt + gs * 8, As + c0 * 8);
    }
#pragma unroll
    for (int it = 0; it < 4; ++it) {
      const int c0 = it * 256 + wave * 64;
      const int idx = c0 + lane;
      const int rr = idx >> 3, cc = idx & 7;
      const int gs = cc ^ (rr & 7);
      gload_lds16(Bbase + (size_t)rr * K + kt + gs * 8, Bs + c0 * 8);
    }
    asm volatile("s_waitcnt vmcnt(0)" ::: "memory");
    __syncthreads();
#pragma unroll
    for (int s = 0; s < 2; ++s) {
      bf16x8 af[4], bfr[4];
#pragma unroll
      for (int mi = 0; mi < 4; ++mi) {
        const int rr = wm * 64 + mi * 16 + r;
        const int ch = (s * 4 + g) ^ (rr & 7);
        af[mi] = *reinterpret_cast<const bf16x8*>(&As[rr * BK + ch * 8]);
      }
#pragma unroll
      for (int ni = 0; ni < 4; ++ni) {
        const int rr = wn * 64 + ni * 16 + r;
        const int ch = (s * 4 + g) ^ (rr & 7);
        bfr[ni] = *reinterpret_cast<const bf16x8*>(&Bs[rr * BK + ch * 8]);
      }
#pragma unroll
      for (int mi = 0; mi < 4; ++mi)
#pragma unroll
        for (int ni = 0; ni < 4; ++ni)
          acc[mi][ni] = __builtin_amdgcn_mfma_f32_16x16x32_bf16(
              af[mi], bfr[ni], acc[mi][ni], 0, 0, 0);
    }
    __syncthreads();
  }

#pragma unroll
  for (int mi = 0; mi < 4; ++mi) {
#pragma unroll
    for (int ni = 0; ni < 4; ++ni) {
      const int grow0 = bm * BM + wm * 64 + mi * 16 + g * 4;
      const int gcol  = bn * BN + wn * 64 + ni * 16 + r;
      const float bv = bias[gcol];
#pragma unroll
      for (int i = 0; i < 4; ++i) {
        const int grow = grow0 + i;
        float v = acc[mi][ni][i] + bv;
        if constexpr (EPI == 0) {
          const int which = gcol >> 10;
          const int c0 = gcol & 1023;
          const int hh = c0 >> 6, dd = c0 & 63;
          const int bb = grow >> 11, t = grow & 2047;
          bf16_t* dst = (which == 0) ? bout0 : (which == 1) ? bout1 : bout2;
          dst[((size_t)(bb * NH + hh) * TT + t) * DH + dd] = (bf16_t)v;
        } else if constexpr (EPI == 1) {
          const size_t o = (size_t)grow * N + gcol;
          fout[o] = v + resid[o];
        } else {
          const float gl = 0.5f * v * (1.0f + erff(v * 0.70710678118654752f));
          bout0[(size_t)grow * N + gcol] = (bf16_t)gl;
        }
      }
    }
  }
}

// ---------------- barrier-free two-pass causal attention with LIF gating ----
// One wave = 32 q-rows. No __syncthreads. K/V fragments direct from global
// (L2-hot). Gated-m matrix goes through a per-wave LDS buffer (same-wave ds
// ordering, no barrier needed). XCD-aware block mapping: 4 heads per XCD.
__global__ __launch_bounds__(256) void attn_lif2(
    const bf16_t* __restrict__ Q, const bf16_t* __restrict__ Km,
    const bf16_t* __restrict__ Vt, bf16_t* __restrict__ Y,
    const float* __restrict__ thrp, const float* __restrict__ leakp,
    const float* __restrict__ steepp)
{
  __shared__ bf16_t Ms[4][32 * 64];   // per-wave gated-m tile, XOR-swizzled
  const int tid  = threadIdx.x;
  const int wave = tid >> 6, lane = tid & 63;
  const int r = lane & 15, g = lane >> 4;

  // block -> (bh, strip) with XCD clustering: xcd = bid%8 owns heads 4*xcd..+3
  const int bid  = blockIdx.x;
  const int xcd  = bid & 7, slot = bid >> 3;          // slot 0..63
  const int bh   = xcd * 4 + (slot >> 4);             // 0..31
  const int strip = (slot & 15) * 4 + wave;           // 0..63 (32 rows each)
  const int hh = bh & (NH - 1), bb = bh >> 4;

  const bf16_t* Qh  = Q  + (size_t)bh * TT * DH;
  const bf16_t* Kh  = Km + (size_t)bh * TT * DH;
  const bf16_t* Vth = Vt + (size_t)bh * TT * DH;      // [DH][TT]

  const float th = fabsf(thrp[hh]) * 0.1f;
  const float lk = 1.0f / (1.0f + expf(-leakp[hh]));
  const float st = log1pf(expf(steepp[hh]));

  const int row0 = strip * 32;
  const int nkt  = (row0 + 31) / 64 + 1;              // causal K-tiles of 64

  // Q fragments in registers for the whole kernel
  bf16x8 qf[2][2];
#pragma unroll
  for (int mi = 0; mi < 2; ++mi)
#pragma unroll
    for (int s = 0; s < 2; ++s)
      qf[mi][s] = *reinterpret_cast<const bf16x8*>(
          Qh + (size_t)(row0 + mi * 16 + r) * DH + s * 32 + g * 8);

  // ---- pass 1: per-lane online max/Z over the lane's own columns ----------
  float runM[8], runZ[8];
#pragma unroll
  for (int ix = 0; ix < 8; ++ix) { runM[ix] = -1e30f; runZ[ix] = 0.f; }

  for (int kt = 0; kt < nkt; ++kt) {
    f32x4 sf[2][4] = {};
#pragma unroll
    for (int s = 0; s < 2; ++s) {
      bf16x8 kf[4];
#pragma unroll
      for (int ni = 0; ni < 4; ++ni)
        kf[ni] = *reinterpret_cast<const bf16x8*>(
            Kh + (size_t)(kt * 64 + ni * 16 + r) * DH + s * 32 + g * 8);
#pragma unroll
      for (int mi = 0; mi < 2; ++mi)
#pragma unroll
        for (int ni = 0; ni < 4; ++ni)
          sf[mi][ni] = __builtin_amdgcn_mfma_f32_16x16x32_bf16(
              qf[mi][s], kf[ni], sf[mi][ni], 0, 0, 0);
    }
#pragma unroll
    for (int mi = 0; mi < 2; ++mi)
#pragma unroll
      for (int i = 0; i < 4; ++i) {
        const int ix = mi * 4 + i;
        const int qrow = row0 + mi * 16 + g * 4 + i;
        float xv[4], mt = -1e30f;
#pragma unroll
        for (int ni = 0; ni < 4; ++ni) {
          const int kcol = kt * 64 + ni * 16 + r;
          const float x = sf[mi][ni][i] * 0.125f;
          xv[ni] = (kcol > qrow) ? -1e30f : x;
          mt = fmaxf(mt, xv[ni]);
        }
        const float nm = fmaxf(runM[ix], mt);
        float z = runZ[ix] * __expf(runM[ix] - nm);
#pragma unroll
        for (int ni = 0; ni < 4; ++ni) z += __expf(xv[ni] - nm);
        runZ[ix] = z; runM[ix] = nm;
      }
  }

  // cross-lane finalize (once per strip, 16-lane groups share a row)
  float M[8], rcpZ[8];
#pragma unroll
  for (int ix = 0; ix < 8; ++ix) {
    float m = runM[ix];
#pragma unroll
    for (int msk = 1; msk < 16; msk <<= 1) m = fmaxf(m, __shfl_xor(m, msk));
    float z = runZ[ix] * __expf(runM[ix] - m);
#pragma unroll
    for (int msk = 1; msk < 16; msk <<= 1) z += __shfl_xor(z, msk);
    M[ix] = m; rcpZ[ix] = 1.0f / z;
  }

  // ---- pass 2: p, LIF gate, m@V, sum(m) ------------------------------------
  f32x4 yacc[2][4] = {};
  float den[8] = {};
  bf16_t* mw = &Ms[wave][0];

  for (int kt = 0; kt < nkt; ++kt) {
    f32x4 sf[2][4] = {};
#pragma unroll
    for (int s = 0; s < 2; ++s) {
      bf16x8 kf[4];
#pragma unroll
      for (int ni = 0; ni < 4; ++ni)
        kf[ni] = *reinterpret_cast<const bf16x8*>(
            Kh + (size_t)(kt * 64 + ni * 16 + r) * DH + s * 32 + g * 8);
#pragma unroll
      for (int mi = 0; mi < 2; ++mi)
#pragma unroll
        for (int ni = 0; ni < 4; ++ni)
          sf[mi][ni] = __builtin_amdgcn_mfma_f32_16x16x32_bf16(
              qf[mi][s], kf[ni], sf[mi][ni], 0, 0, 0);
    }
#pragma unroll
    for (int mi = 0; mi < 2; ++mi)
#pragma unroll
      for (int i = 0; i < 4; ++i) {
        const int ix = mi * 4 + i;
        const int qrow = row0 + mi * 16 + g * 4 + i;
        const int rr = mi * 16 + g * 4 + i;
#pragma unroll
        for (int ni = 0; ni < 4; ++ni) {
          const int kcol = kt * 64 + ni * 16 + r;
          const float x = sf[mi][ni][i] * 0.125f;
          const float p = (kcol > qrow) ? 0.f : __expf(x - M[ix]) * rcpZ[ix];
          const float fire = 1.0f / (1.0f + __expf(-st * (p - th)));
          const float mv = p * (lk + (1.0f - lk) * fire);
          den[ix] += mv;
          const int cc = ni * 16 + r;
          const int ch = (cc >> 3) ^ (rr & 7);
          mw[rr * 64 + ch * 8 + (cc & 7)] = (bf16_t)mv;
        }
      }
    // same-wave LDS write->read: in-order ds queue, no barrier needed
#pragma unroll
    for (int s = 0; s < 2; ++s) {
      bf16x8 mf[2], vf[4];
#pragma unroll
      for (int mi = 0; mi < 2; ++mi) {
        const int rr = mi * 16 + r;
        const int ch = (s * 4 + g) ^ (rr & 7);
        mf[mi] = *reinterpret_cast<const bf16x8*>(&mw[rr * 64 + ch * 8]);
      }
#pragma unroll
      for (int ni = 0; ni < 4; ++ni)
        vf[ni] = *reinterpret_cast<const bf16x8*>(
            Vth + (size_t)(ni * 16 + r) * TT + kt * 64 + s * 32 + g * 8);
#pragma unroll
      for (int mi = 0; mi < 2; ++mi)
#pragma unroll
        for (int ni = 0; ni < 4; ++ni)
          yacc[mi][ni] = __builtin_amdgcn_mfma_f32_16x16x32_bf16(
              mf[mi], vf[ni], yacc[mi][ni], 0, 0, 0);
    }
  }

  // renormalize and write Y as [B][T][H*D]
#pragma unroll
  for (int ix = 0; ix < 8; ++ix) {
    float d = den[ix];
#pragma unroll
    for (int msk = 1; msk < 16; msk <<= 1) d += __shfl_xor(d, msk);
    den[ix] = 1.0f / (d + 1e-8f);
  }
#pragma unroll
  for (int mi = 0; mi < 2; ++mi)
#pragma unroll
    for (int ni = 0; ni < 4; ++ni)
#pragma unroll
      for (int i = 0; i < 4; ++i) {
        const int t  = row0 + mi * 16 + g * 4 + i;
        const int dd = ni * 16 + r;
        const float yv = yacc[mi][ni][i] * den[mi * 4 + i];
        Y[((size_t)(bb * TT + t)) * C_ + hh * DH + dd] = (bf16_t)yv;
      }
}

// ---------------------------------------------------------------------------
extern "C" void kernel_launch(void* const* d_in, const int* in_sizes, int n_in,
                              void* d_out, int out_size, void* d_ws, size_t ws_size,
                              hipStream_t stream)
{
  const float* x      = (const float*)d_in[0];
  const float* ln1_w  = (const float*)d_in[1];
  const float* ln1_b  = (const float*)d_in[2];
  const float* w_attn = (const float*)d_in[3];
  const float* b_attn = (const float*)d_in[4];
  const float* w_proj = (const float*)d_in[5];
  const float* b_proj = (const float*)d_in[6];
  const float* thr    = (const float*)d_in[7];
  const float* leak   = (const float*)d_in[8];
  const float* steep  = (const float*)d_in[9];
  const float* ln2_w  = (const float*)d_in[10];
  const float* ln2_b  = (const float*)d_in[11];
  const float* w_fc   = (const float*)d_in[12];
  const float* b_fc   = (const float*)d_in[13];
  const float* w_mlp  = (const float*)d_in[14];
  const float* b_mlp  = (const float*)d_in[15];

  char* ws = (char*)d_ws;
  bf16_t* q    = (bf16_t*)(ws + 0);          //  8 MB
  bf16_t* k    = (bf16_t*)(ws + 8388608);    //  8 MB
  bf16_t* v    = (bf16_t*)(ws + 16777216);   //  8 MB
  bf16_t* vT   = (bf16_t*)(ws + 25165824);   //  8 MB
  bf16_t* gbuf = (bf16_t*)(ws + 0);          // 32 MB, aliases q/k/v/vT (dead)
  bf16_t* hbuf = (bf16_t*)(ws + 33554432);   //  8 MB, h -> y -> h2
  float*  x2   = (float*) (ws + 41943040);   // 16 MB
  bf16_t* wT_attn = (bf16_t*)(ws + 58720256); // 6 MB
  bf16_t* wT_proj = (bf16_t*)(ws + 65011712); // 2 MB
  bf16_t* wT_fc   = (bf16_t*)(ws + 67108864); // 8 MB
  bf16_t* wT_mlp  = (bf16_t*)(ws + 75497472); // 8 MB -> 80 MB total

  float* out = (float*)d_out;

  ln_bf16<<<dim3(MROWS), dim3(256), 0, stream>>>(x, ln1_w, ln1_b, hbuf);
  transpose_w<<<dim3(96, 32),  dim3(256), 0, stream>>>(w_attn, wT_attn, 1024, 3072);
  transpose_w<<<dim3(32, 32),  dim3(256), 0, stream>>>(w_proj, wT_proj, 1024, 1024);
  transpose_w<<<dim3(128, 32), dim3(256), 0, stream>>>(w_fc,   wT_fc,   1024, 4096);
  transpose_w<<<dim3(32, 128), dim3(256), 0, stream>>>(w_mlp,  wT_mlp,  4096, 1024);

  gemm_bf16<0><<<dim3(32, 24), dim3(256), 0, stream>>>(
      hbuf, wT_attn, b_attn, nullptr, nullptr, q, k, v, MROWS, 3072, 1024);
  transpose_v<<<dim3(64, 2, 32), dim3(256), 0, stream>>>(v, vT);

  // barrier-free attention: 512 blocks x 4 independent wave-tasks
  attn_lif2<<<dim3(512), dim3(256), 0, stream>>>(q, k, vT, hbuf, thr, leak, steep);

  gemm_bf16<1><<<dim3(32, 8), dim3(256), 0, stream>>>(
      hbuf, wT_proj, b_proj, x, x2, nullptr, nullptr, nullptr, MROWS, 1024, 1024);

  ln_bf16<<<dim3(MROWS), dim3(256), 0, stream>>>(x2, ln2_w, ln2_b, hbuf);

  gemm_bf16<2><<<dim3(32, 32), dim3(256), 0, stream>>>(
      hbuf, wT_fc, b_fc, nullptr, nullptr, gbuf, nullptr, nullptr, MROWS, 4096, 1024);

  gemm_bf16<1><<<dim3(32, 8), dim3(256), 0, stream>>>(
      gbuf, wT_mlp, b_mlp, x2, out, nullptr, nullptr, nullptr, MROWS, 1024, 4096);
}

// Round 3
// 409.938 us; speedup vs baseline: 1.2964x; 1.0512x over previous
//
#include <hip/hip_runtime.h>
#include <hip/hip_bf16.h>
#include <math.h>

typedef __bf16 bf16_t;
typedef __bf16 bf16x8 __attribute__((ext_vector_type(8)));
typedef __bf16 bf16x4 __attribute__((ext_vector_type(4)));
typedef float  f32x4  __attribute__((ext_vector_type(4)));
typedef unsigned int u32;

static constexpr int C_    = 1024;
static constexpr int NH    = 16;
static constexpr int DH    = 64;
static constexpr int BB    = 2;
static constexpr int TT    = 2048;
static constexpr int MROWS = BB * TT;   // 4096

// ---------------- async global->LDS, 16B per lane, wave-uniform LDS base ----
__device__ __forceinline__ void gload_lds16(const bf16_t* src, bf16_t* dst) {
  __builtin_amdgcn_global_load_lds(
      (const __attribute__((address_space(1))) u32*)(src),
      (__attribute__((address_space(3))) u32*)(dst),
      16, 0, 0);
}

// ---------------- LayerNorm (fp32 in) -> bf16 out ---------------------------
__global__ __launch_bounds__(256) void ln_bf16(
    const float* __restrict__ x, const float* __restrict__ w,
    const float* __restrict__ b, bf16_t* __restrict__ out)
{
  const int row = blockIdx.x;
  const int tid = threadIdx.x;
  const float4 v = reinterpret_cast<const float4*>(x + (size_t)row * C_)[tid];
  float s  = v.x + v.y + v.z + v.w;
  float s2 = v.x*v.x + v.y*v.y + v.z*v.z + v.w*v.w;
#pragma unroll
  for (int m = 1; m < 64; m <<= 1) { s += __shfl_xor(s, m); s2 += __shfl_xor(s2, m); }
  __shared__ float red[8];
  const int wv = tid >> 6;
  if ((tid & 63) == 0) { red[wv] = s; red[4 + wv] = s2; }
  __syncthreads();
  s  = red[0] + red[1] + red[2] + red[3];
  s2 = red[4] + red[5] + red[6] + red[7];
  const float mu   = s * (1.0f / C_);
  const float rstd = rsqrtf(s2 * (1.0f / C_) - mu * mu + 1e-5f);
  const float4 wv4 = reinterpret_cast<const float4*>(w)[tid];
  const float4 bv4 = reinterpret_cast<const float4*>(b)[tid];
  bf16x4 o;
  o[0] = (bf16_t)((v.x - mu) * rstd * wv4.x + bv4.x);
  o[1] = (bf16_t)((v.y - mu) * rstd * wv4.y + bv4.y);
  o[2] = (bf16_t)((v.z - mu) * rstd * wv4.z + bv4.z);
  o[3] = (bf16_t)((v.w - mu) * rstd * wv4.w + bv4.w);
  *reinterpret_cast<bf16x4*>(out + (size_t)row * C_ + tid * 4) = o;
}

// ---------------- weight transpose+convert: fp32 [K][N] -> bf16 [N][K] ------
__global__ __launch_bounds__(256) void transpose_w(
    const float* __restrict__ in, bf16_t* __restrict__ out, int K, int N)
{
  __shared__ float tile[32][33];
  const int tx = threadIdx.x & 31, ty = threadIdx.x >> 5;
  const int n0 = blockIdx.x * 32, k0 = blockIdx.y * 32;
#pragma unroll
  for (int i = 0; i < 4; ++i)
    tile[ty + i * 8][tx] = in[(size_t)(k0 + ty + i * 8) * N + n0 + tx];
  __syncthreads();
#pragma unroll
  for (int i = 0; i < 4; ++i)
    out[(size_t)(n0 + ty + i * 8) * K + k0 + tx] = (bf16_t)tile[tx][ty + i * 8];
}

// ---------------- V transpose: bf16 [BH][T][D] -> [BH][D][T] -----------------
__global__ __launch_bounds__(256) void transpose_v(
    const bf16_t* __restrict__ in, bf16_t* __restrict__ out)
{
  __shared__ bf16_t tile[32][33];
  const int bh = blockIdx.z;
  const bf16_t* src = in  + (size_t)bh * TT * DH;
  bf16_t*       dst = out + (size_t)bh * TT * DH;
  const int tx = threadIdx.x & 31, ty = threadIdx.x >> 5;
  const int t0 = blockIdx.x * 32, d0 = blockIdx.y * 32;
#pragma unroll
  for (int i = 0; i < 4; ++i)
    tile[ty + i * 8][tx] = src[(size_t)(t0 + ty + i * 8) * DH + d0 + tx];
  __syncthreads();
#pragma unroll
  for (int i = 0; i < 4; ++i)
    dst[(size_t)(d0 + ty + i * 8) * TT + t0 + tx] = tile[tx][ty + i * 8];
}

// ---------------- GEMM: C = A[M][K] * Bt[N][K]^T + bias, epilogues ----------
template<int EPI>
__global__ __launch_bounds__(256) void gemm_bf16(
    const bf16_t* __restrict__ A, const bf16_t* __restrict__ Bt,
    const float* __restrict__ bias, const float* __restrict__ resid,
    float* __restrict__ fout, bf16_t* __restrict__ bout0,
    bf16_t* __restrict__ bout1, bf16_t* __restrict__ bout2,
    int M, int N, int K)
{
  constexpr int BM = 128, BN = 128, BK = 64;
  __shared__ bf16_t As[BM * BK];
  __shared__ bf16_t Bs[BN * BK];
  const int tid  = threadIdx.x;
  const int wave = tid >> 6, lane = tid & 63;
  const int r = lane & 15, g = lane >> 4;
  const int wm = wave >> 1, wn = wave & 1;
  const int bm = blockIdx.x, bn = blockIdx.y;

  const bf16_t* Abase = A  + (size_t)bm * BM * K;
  const bf16_t* Bbase = Bt + (size_t)bn * BN * K;

  f32x4 acc[4][4] = {};

  for (int kt = 0; kt < K; kt += BK) {
#pragma unroll
    for (int it = 0; it < 4; ++it) {
      const int c0 = it * 256 + wave * 64;
      const int idx = c0 + lane;
      const int rr = idx >> 3, cc = idx & 7;
      const int gs = cc ^ (rr & 7);
      gload_lds16(Abase + (size_t)rr * K + kt + gs * 8, As + c0 * 8);
    }
#pragma unroll
    for (int it = 0; it < 4; ++it) {
      const int c0 = it * 256 + wave * 64;
      const int idx = c0 + lane;
      const int rr = idx >> 3, cc = idx & 7;
      const int gs = cc ^ (rr & 7);
      gload_lds16(Bbase + (size_t)rr * K + kt + gs * 8, Bs + c0 * 8);
    }
    asm volatile("s_waitcnt vmcnt(0)" ::: "memory");
    __syncthreads();
#pragma unroll
    for (int s = 0; s < 2; ++s) {
      bf16x8 af[4], bfr[4];
#pragma unroll
      for (int mi = 0; mi < 4; ++mi) {
        const int rr = wm * 64 + mi * 16 + r;
        const int ch = (s * 4 + g) ^ (rr & 7);
        af[mi] = *reinterpret_cast<const bf16x8*>(&As[rr * BK + ch * 8]);
      }
#pragma unroll
      for (int ni = 0; ni < 4; ++ni) {
        const int rr = wn * 64 + ni * 16 + r;
        const int ch = (s * 4 + g) ^ (rr & 7);
        bfr[ni] = *reinterpret_cast<const bf16x8*>(&Bs[rr * BK + ch * 8]);
      }
#pragma unroll
      for (int mi = 0; mi < 4; ++mi)
#pragma unroll
        for (int ni = 0; ni < 4; ++ni)
          acc[mi][ni] = __builtin_amdgcn_mfma_f32_16x16x32_bf16(
              af[mi], bfr[ni], acc[mi][ni], 0, 0, 0);
    }
    __syncthreads();
  }

#pragma unroll
  for (int mi = 0; mi < 4; ++mi) {
#pragma unroll
    for (int ni = 0; ni < 4; ++ni) {
      const int grow0 = bm * BM + wm * 64 + mi * 16 + g * 4;
      const int gcol  = bn * BN + wn * 64 + ni * 16 + r;
      const float bv = bias[gcol];
#pragma unroll
      for (int i = 0; i < 4; ++i) {
        const int grow = grow0 + i;
        float v = acc[mi][ni][i] + bv;
        if constexpr (EPI == 0) {
          const int which = gcol >> 10;
          const int c0 = gcol & 1023;
          const int hh = c0 >> 6, dd = c0 & 63;
          const int bb = grow >> 11, t = grow & 2047;
          bf16_t* dst = (which == 0) ? bout0 : (which == 1) ? bout1 : bout2;
          dst[((size_t)(bb * NH + hh) * TT + t) * DH + dd] = (bf16_t)v;
        } else if constexpr (EPI == 1) {
          const size_t o = (size_t)grow * N + gcol;
          fout[o] = v + resid[o];
        } else {
          const float gl = 0.5f * v * (1.0f + erff(v * 0.70710678118654752f));
          bout0[(size_t)grow * N + gcol] = (bf16_t)gl;
        }
      }
    }
  }
}

// ---------------- fully-resident 1-wave attention with LIF gating -----------
// 4096 blocks x 64 threads; one wave owns 16 q-rows; no __syncthreads at all.
// All waves resident simultaneously (<=128 VGPR -> 4 waves/SIMD -> 16/CU).
// K/V direct from global (L2-hot, 4 heads pinned per XCD); gated-m through a
// tiny per-block LDS buffer (same-wave ds ordering needs no barrier).
__global__ __launch_bounds__(64, 4) void attn_lif3(
    const bf16_t* __restrict__ Q, const bf16_t* __restrict__ Km,
    const bf16_t* __restrict__ Vt, bf16_t* __restrict__ Y,
    const float* __restrict__ thrp, const float* __restrict__ leakp,
    const float* __restrict__ steepp)
{
  __shared__ bf16_t Ms[16 * 64];      // gated-m tile, XOR-swizzled (2 KB)
  const int lane = threadIdx.x;
  const int r = lane & 15, g = lane >> 4;

  // bid -> (bh, strip): 4 heads per XCD (bid&7), strips spread across CUs
  const int bid = blockIdx.x;
  const int xq  = bid >> 3;
  const int bh  = (bid & 7) * 4 + (xq & 3);   // 0..31
  const int strip = xq >> 2;                  // 0..127 (16 rows each)
  const int hh = bh & (NH - 1), bb = bh >> 4;

  const bf16_t* Qh  = Q  + (size_t)bh * TT * DH;
  const bf16_t* Kh  = Km + (size_t)bh * TT * DH;
  const bf16_t* Vth = Vt + (size_t)bh * TT * DH;   // [DH][TT]

  const float th = fabsf(thrp[hh]) * 0.1f;
  const float lk = 1.0f / (1.0f + expf(-leakp[hh]));
  const float st = log1pf(expf(steepp[hh]));

  const int row0 = strip * 16;
  const int nkt  = strip / 4 + 1;             // causal K-tiles of 64

  // Q fragments in registers for the whole kernel (A-frag: row=r, k=g*8+j+32s)
  bf16x8 qf[2];
#pragma unroll
  for (int s = 0; s < 2; ++s)
    qf[s] = *reinterpret_cast<const bf16x8*>(
        Qh + (size_t)(row0 + r) * DH + s * 32 + g * 8);

  // ---- pass 1: per-lane online max/Z over the lane's own columns ----------
  float runM[4], runZ[4];
#pragma unroll
  for (int i = 0; i < 4; ++i) { runM[i] = -1e30f; runZ[i] = 0.f; }

  for (int kt = 0; kt < nkt; ++kt) {
    f32x4 sf[4] = {};
#pragma unroll
    for (int s = 0; s < 2; ++s) {
      bf16x8 kf[4];
#pragma unroll
      for (int ni = 0; ni < 4; ++ni)
        kf[ni] = *reinterpret_cast<const bf16x8*>(
            Kh + (size_t)(kt * 64 + ni * 16 + r) * DH + s * 32 + g * 8);
#pragma unroll
      for (int ni = 0; ni < 4; ++ni)
        sf[ni] = __builtin_amdgcn_mfma_f32_16x16x32_bf16(
            qf[s], kf[ni], sf[ni], 0, 0, 0);
    }
#pragma unroll
    for (int i = 0; i < 4; ++i) {
      const int qrow = row0 + g * 4 + i;
      float xv[4], mt = -1e30f;
#pragma unroll
      for (int ni = 0; ni < 4; ++ni) {
        const int kcol = kt * 64 + ni * 16 + r;
        const float x = sf[ni][i] * 0.125f;
        xv[ni] = (kcol > qrow) ? -1e30f : x;
        mt = fmaxf(mt, xv[ni]);
      }
      const float nm = fmaxf(runM[i], mt);
      float z = runZ[i] * __expf(runM[i] - nm);
#pragma unroll
      for (int ni = 0; ni < 4; ++ni) z += __expf(xv[ni] - nm);
      runZ[i] = z; runM[i] = nm;
    }
  }

  // cross-lane finalize (16-lane groups share a q-row)
  float M[4], rcpZ[4];
#pragma unroll
  for (int i = 0; i < 4; ++i) {
    float m = runM[i];
#pragma unroll
    for (int msk = 1; msk < 16; msk <<= 1) m = fmaxf(m, __shfl_xor(m, msk));
    float z = runZ[i] * __expf(runM[i] - m);
#pragma unroll
    for (int msk = 1; msk < 16; msk <<= 1) z += __shfl_xor(z, msk);
    M[i] = m; rcpZ[i] = 1.0f / z;
  }

  // ---- pass 2: p, LIF gate, m@V, sum(m) ------------------------------------
  f32x4 yacc[4] = {};
  float den[4] = {};

  for (int kt = 0; kt < nkt; ++kt) {
    f32x4 sf[4] = {};
#pragma unroll
    for (int s = 0; s < 2; ++s) {
      bf16x8 kf[4];
#pragma unroll
      for (int ni = 0; ni < 4; ++ni)
        kf[ni] = *reinterpret_cast<const bf16x8*>(
            Kh + (size_t)(kt * 64 + ni * 16 + r) * DH + s * 32 + g * 8);
#pragma unroll
      for (int ni = 0; ni < 4; ++ni)
        sf[ni] = __builtin_amdgcn_mfma_f32_16x16x32_bf16(
            qf[s], kf[ni], sf[ni], 0, 0, 0);
    }
#pragma unroll
    for (int i = 0; i < 4; ++i) {
      const int qrow = row0 + g * 4 + i;
      const int rr = g * 4 + i;
#pragma unroll
      for (int ni = 0; ni < 4; ++ni) {
        const int kcol = kt * 64 + ni * 16 + r;
        const float x = sf[ni][i] * 0.125f;
        const float p = (kcol > qrow) ? 0.f : __expf(x - M[i]) * rcpZ[i];
        const float fire = 1.0f / (1.0f + __expf(-st * (p - th)));
        const float mv = p * (lk + (1.0f - lk) * fire);
        den[i] += mv;
        const int cc = ni * 16 + r;
        const int ch = (cc >> 3) ^ (rr & 7);
        Ms[rr * 64 + ch * 8 + (cc & 7)] = (bf16_t)mv;
      }
    }
    // same-wave LDS write->read: in-order ds queue, no barrier needed
#pragma unroll
    for (int s = 0; s < 2; ++s) {
      bf16x8 mf, vf[4];
      {
        const int ch = (s * 4 + g) ^ (r & 7);
        mf = *reinterpret_cast<const bf16x8*>(&Ms[r * 64 + ch * 8]);
      }
#pragma unroll
      for (int ni = 0; ni < 4; ++ni)
        vf[ni] = *reinterpret_cast<const bf16x8*>(
            Vth + (size_t)(ni * 16 + r) * TT + kt * 64 + s * 32 + g * 8);
#pragma unroll
      for (int ni = 0; ni < 4; ++ni)
        yacc[ni] = __builtin_amdgcn_mfma_f32_16x16x32_bf16(
            mf, vf[ni], yacc[ni], 0, 0, 0);
    }
  }

  // renormalize and write Y as [B][T][H*D]
#pragma unroll
  for (int i = 0; i < 4; ++i) {
    float d = den[i];
#pragma unroll
    for (int msk = 1; msk < 16; msk <<= 1) d += __shfl_xor(d, msk);
    den[i] = 1.0f / (d + 1e-8f);
  }
#pragma unroll
  for (int ni = 0; ni < 4; ++ni)
#pragma unroll
    for (int i = 0; i < 4; ++i) {
      const int t  = row0 + g * 4 + i;
      const int dd = ni * 16 + r;
      const float yv = yacc[ni][i] * den[i];
      Y[((size_t)(bb * TT + t)) * C_ + hh * DH + dd] = (bf16_t)yv;
    }
}

// ---------------------------------------------------------------------------
extern "C" void kernel_launch(void* const* d_in, const int* in_sizes, int n_in,
                              void* d_out, int out_size, void* d_ws, size_t ws_size,
                              hipStream_t stream)
{
  const float* x      = (const float*)d_in[0];
  const float* ln1_w  = (const float*)d_in[1];
  const float* ln1_b  = (const float*)d_in[2];
  const float* w_attn = (const float*)d_in[3];
  const float* b_attn = (const float*)d_in[4];
  const float* w_proj = (const float*)d_in[5];
  const float* b_proj = (const float*)d_in[6];
  const float* thr    = (const float*)d_in[7];
  const float* leak   = (const float*)d_in[8];
  const float* steep  = (const float*)d_in[9];
  const float* ln2_w  = (const float*)d_in[10];
  const float* ln2_b  = (const float*)d_in[11];
  const float* w_fc   = (const float*)d_in[12];
  const float* b_fc   = (const float*)d_in[13];
  const float* w_mlp  = (const float*)d_in[14];
  const float* b_mlp  = (const float*)d_in[15];

  char* ws = (char*)d_ws;
  bf16_t* q    = (bf16_t*)(ws + 0);          //  8 MB
  bf16_t* k    = (bf16_t*)(ws + 8388608);    //  8 MB
  bf16_t* v    = (bf16_t*)(ws + 16777216);   //  8 MB
  bf16_t* vT   = (bf16_t*)(ws + 25165824);   //  8 MB
  bf16_t* gbuf = (bf16_t*)(ws + 0);          // 32 MB, aliases q/k/v/vT (dead)
  bf16_t* hbuf = (bf16_t*)(ws + 33554432);   //  8 MB, h -> y -> h2
  float*  x2   = (float*) (ws + 41943040);   // 16 MB
  bf16_t* wT_attn = (bf16_t*)(ws + 58720256); // 6 MB
  bf16_t* wT_proj = (bf16_t*)(ws + 65011712); // 2 MB
  bf16_t* wT_fc   = (bf16_t*)(ws + 67108864); // 8 MB
  bf16_t* wT_mlp  = (bf16_t*)(ws + 75497472); // 8 MB -> 80 MB total

  float* out = (float*)d_out;

  ln_bf16<<<dim3(MROWS), dim3(256), 0, stream>>>(x, ln1_w, ln1_b, hbuf);
  transpose_w<<<dim3(96, 32),  dim3(256), 0, stream>>>(w_attn, wT_attn, 1024, 3072);
  transpose_w<<<dim3(32, 32),  dim3(256), 0, stream>>>(w_proj, wT_proj, 1024, 1024);
  transpose_w<<<dim3(128, 32), dim3(256), 0, stream>>>(w_fc,   wT_fc,   1024, 4096);
  transpose_w<<<dim3(32, 128), dim3(256), 0, stream>>>(w_mlp,  wT_mlp,  4096, 1024);

  gemm_bf16<0><<<dim3(32, 24), dim3(256), 0, stream>>>(
      hbuf, wT_attn, b_attn, nullptr, nullptr, q, k, v, MROWS, 3072, 1024);
  transpose_v<<<dim3(64, 2, 32), dim3(256), 0, stream>>>(v, vT);

  // fully-resident attention: 4096 independent 1-wave blocks
  attn_lif3<<<dim3(4096), dim3(64), 0, stream>>>(q, k, vT, hbuf, thr, leak, steep);

  gemm_bf16<1><<<dim3(32, 8), dim3(256), 0, stream>>>(
      hbuf, wT_proj, b_proj, x, x2, nullptr, nullptr, nullptr, MROWS, 1024, 1024);

  ln_bf16<<<dim3(MROWS), dim3(256), 0, stream>>>(x2, ln2_w, ln2_b, hbuf);

  gemm_bf16<2><<<dim3(32, 32), dim3(256), 0, stream>>>(
      hbuf, wT_fc, b_fc, nullptr, nullptr, gbuf, nullptr, nullptr, MROWS, 4096, 1024);

  gemm_bf16<1><<<dim3(32, 8), dim3(256), 0, stream>>>(
      gbuf, wT_mlp, b_mlp, x2, out, nullptr, nullptr, nullptr, MROWS, 1024, 4096);
}